// Round 8
// baseline (812.776 us; speedup 1.0000x reference)
//
#include <hip/hip_runtime.h>
#include <hip/hip_fp16.h>
#include <math.h>

#define DIM 128
#define SQL 4096
#define NBATCH 4
#define NROW (NBATCH*SQL)          // 16384 total rows
#define SCALE 0.08838834764831845f // 1/sqrt(128)
#define KSPLIT 8                   // K-range split across blocks
#define PREPBLK (NROW/16)          // 1024 prep blocks (proj + mask slice)

typedef _Float16 f16;
typedef _Float16 f16x4 __attribute__((ext_vector_type(4)));
typedef _Float16 f16x8 __attribute__((ext_vector_type(8)));
typedef float f32x4 __attribute__((ext_vector_type(4)));

__device__ __forceinline__ f32x4 mfma16(f16x8 a, f16x8 b, f32x4 c) {
  return __builtin_amdgcn_mfma_f32_16x16x32_f16(a, b, c, 0, 0, 0);
}

// ---------------------------------------------------------------------------
// Kernel 1 "prep": each of 1024 blocks does BOTH a proj tile (16 rows) and a
// grid-stride mask-pack slice, order staggered by block parity so the
// HBM-stream (mask) and VALU/LDS (proj) phases overlap across waves/blocks.
//
// proj: K = inp*Wk^T, V = inp*Wv^T (fp32 math), emit
//   q16[row][d]  = fp16(inp)
//   kfrag        = fp16(K) in MFMA A-frag order [rt][c][quad][l15][8] (4KB/t)
//   vfrag        = fp16(V) in MFMA B-frag order [kt64][dt][kc2][q][l15][8]
// so every hot-loop fragment load in `fused` is base + lane*16B.
//
// maskpack: 1 bit/elem; runtime-detect int32 vs byte layout (64 random 0/1
// BYTES viewed as u32 never all <=1; int32 0/1 always); byte-nonzero via
// carry trick (`!=0` semantics).
// ---------------------------------------------------------------------------
__global__ __launch_bounds__(256) void prep(const float* __restrict__ inp,
                                            const float* __restrict__ wk,
                                            const float* __restrict__ wv,
                                            const void* __restrict__ mask,
                                            f16* __restrict__ q16,
                                            f16* __restrict__ kfrag,
                                            f16* __restrict__ vfrag,
                                            unsigned long long* __restrict__ mbits,
                                            int n) {
  __shared__ float s_in[16][DIM];                 // 8 KB
  __shared__ __align__(16) f16 s_vt[DIM][16];     // 4 KB V^T staging
  __shared__ __align__(16) f16 s_kf[2048];        // 4 KB K fragment staging
  __shared__ int s_is32;
  const int t = threadIdx.x;
  const int bid = blockIdx.x;
  const int rowbase = bid * 16;
  const int e = t & 127;
  const int half_ = t >> 7;

  if (t == 0) {
    const unsigned int* w = (const unsigned int*)mask;
    int ok = 1;
    for (int i = 0; i < 64; ++i) ok &= (w[i] <= 1u);
    s_is32 = ok;
  }
  for (int r = half_; r < 16; r += 2)
    s_in[r][e] = inp[(size_t)(rowbase + r) * DIM + e];
  __syncthreads();

  auto maskwork = [&]() {
    const int stride = PREPBLK * 256;
    const uint4* mv = (const uint4*)mask;
    if (s_is32) {
      const int nvec = n >> 2;                  // 16M, 64 iters/thread
      for (int i = bid * 256 + t; i < nvec; i += stride) {
        const uint4 v = mv[i];
        const unsigned int nib = (v.x != 0u) | ((v.y != 0u) << 1) |
                                 ((v.z != 0u) << 2) | ((v.w != 0u) << 3);
        unsigned long long bits = (unsigned long long)nib << ((i & 15) * 4);
        bits |= __shfl_xor(bits, 1);
        bits |= __shfl_xor(bits, 2);
        bits |= __shfl_xor(bits, 4);
        bits |= __shfl_xor(bits, 8);
        if ((t & 15) == 0) mbits[i >> 4] = bits; // word = (i*4)>>6
      }
    } else {
      const int nvec = n >> 4;                  // 4M, 16 iters/thread
      for (int i = bid * 256 + t; i < nvec; i += stride) {
        const uint4 v = mv[i];
        const unsigned int M = 0x01020408u;
        unsigned int x;
        x = ((v.x | ((v.x & 0x7F7F7F7Fu) + 0x7F7F7F7Fu)) >> 7) & 0x01010101u;
        const unsigned int n0 = ((x * M) >> 24) & 0xFu;
        x = ((v.y | ((v.y & 0x7F7F7F7Fu) + 0x7F7F7F7Fu)) >> 7) & 0x01010101u;
        const unsigned int n1 = ((x * M) >> 24) & 0xFu;
        x = ((v.z | ((v.z & 0x7F7F7F7Fu) + 0x7F7F7F7Fu)) >> 7) & 0x01010101u;
        const unsigned int n2 = ((x * M) >> 24) & 0xFu;
        x = ((v.w | ((v.w & 0x7F7F7F7Fu) + 0x7F7F7F7Fu)) >> 7) & 0x01010101u;
        const unsigned int n3 = ((x * M) >> 24) & 0xFu;
        const unsigned int b16 = n0 | (n1 << 4) | (n2 << 8) | (n3 << 12);
        unsigned long long bits = (unsigned long long)b16 << ((i & 3) * 16);
        bits |= __shfl_xor(bits, 1);
        bits |= __shfl_xor(bits, 2);
        if ((t & 3) == 0) mbits[i >> 2] = bits;  // word = (i*16)>>6
      }
    }
  };

  auto projcompute = [&]() {
    float ak[8], av[8];
#pragma unroll
    for (int i = 0; i < 8; ++i) { ak[i] = 0.f; av[i] = 0.f; }
    for (int d0 = 0; d0 < DIM; d0 += 8) {
      float wkl[8], wvl[8];
#pragma unroll
      for (int j = 0; j < 8; ++j) {
        wkl[j] = wk[(size_t)e * DIM + d0 + j];
        wvl[j] = wv[(size_t)e * DIM + d0 + j];
      }
#pragma unroll
      for (int i = 0; i < 8; ++i) {
        const int r = half_ * 8 + i;
#pragma unroll
        for (int j = 0; j < 8; ++j) {
          const float x = s_in[r][d0 + j];
          ak[i] += x * wkl[j];
          av[i] += x * wvl[j];
        }
      }
    }
    // col e decomposes as c=e>>5 (A-reg), quad=(e>>3)&3, j=e&7
    const int koff = (e >> 5) * 512 + ((e >> 3) & 3) * 128 + (e & 7);
#pragma unroll
    for (int i = 0; i < 8; ++i) {
      const int r = half_ * 8 + i;              // l15 = row within tile
      s_kf[koff + r * 8] = (f16)ak[i];
      q16[(size_t)(rowbase + r) * DIM + e] = (f16)s_in[r][e];
      s_vt[e][r] = (f16)av[i];
    }
  };

  auto projcopyout = [&]() {
    // kfrag copyout: 2048 halfs contiguous, 16B per thread
    *(f16x8*)(kfrag + ((size_t)(rowbase >> 4)) * 2048 + t * 8) =
        *(const f16x8*)&s_kf[t * 8];
    // vfrag copyout: 16 seq-rows -> (kc2,qh) slot of the 64-row tile
    const int b    = rowbase / SQL;
    const int srow = rowbase % SQL;
    const int m    = (srow >> 4) & 3;
    const int kc2_ = m >> 1, qh = m & 1;
    const int dt_ = t >> 5, h8 = (t >> 4) & 1, l15_ = t & 15;
    const f16x8 vv = *(const f16x8*)&s_vt[dt_ * 16 + l15_][h8 * 8];
    *(f16x8*)(vfrag + ((size_t)b * 64 + (srow >> 6)) * 8192 +
              dt_ * 1024 + kc2_ * 512 + (2 * qh + h8) * 128 + l15_ * 8) = vv;
  };

  if (bid & 1) {           // odd blocks: mask first, then proj
    maskwork();
    projcompute();
    __syncthreads();
    projcopyout();
  } else {                 // even blocks: proj first, then mask
    projcompute();
    __syncthreads();
    projcopyout();
    maskwork();
  }
}

// ---------------------------------------------------------------------------
// Kernel 2: single pass over K.  Wave owns 16 q-rows; block = 64 rows;
// KSPLIT=8 k-chunks across blocks (grid 2048, 8 tiles/wave); zero barriers.
// UNROLL-2: two k-tiles per loop iter with separate pbuf slices -> two
// independent QK->exp->spill->PV chains in flight per wave (compiler
// overlaps t+1's QK loads/MFMA under t's exp/LDS waits).
// All K/V fragment loads LANE-LINEAR 16B.  e = exp(s) unnormalized;
// lpart[kc][row] partials; opart[kc][row][d] = e16*V partials; spill e16
// (SPILLF16=1, non-NT so it stays L3-resident for attnscale) or fp32 e
// into attn (=0).
// ---------------------------------------------------------------------------
template<int SPILLF16>
__global__ __launch_bounds__(256) void fused(const f16* __restrict__ q16,
                                             const f16* __restrict__ kfrag,
                                             const f16* __restrict__ vfrag,
                                             const unsigned long long* __restrict__ mbits,
                                             float* __restrict__ lpart,
                                             float* __restrict__ opart,
                                             f16* __restrict__ p16,
                                             float* __restrict__ attn) {
  __shared__ __align__(16) f16 pbuf[4][2][16][72]; // 18.4 KB, wave-private
  const int kc      = blockIdx.x & (KSPLIT - 1);
  const int blkrow  = (blockIdx.x >> 3) * 64;      // 64 q-rows per block
  const int b = blkrow / SQL;
  const int lane = threadIdx.x & 63;
  const int w = threadIdx.x >> 6;
  const int rowbase = blkrow + w * 16;             // this wave's 16 rows
  const int l15 = lane & 15, quad = lane >> 4;

  f16x8 qa[4];
  {
    const f16* qp = q16 + (size_t)(rowbase + l15) * DIM + quad * 8;
#pragma unroll
    for (int c = 0; c < 4; ++c) qa[c] = *(const f16x8*)(qp + c * 32);
  }

  float l[4];
#pragma unroll
  for (int r = 0; r < 4; ++r) l[r] = 0.f;

  f32x4 oacc[8];
#pragma unroll
  for (int dt = 0; dt < 8; ++dt) oacc[dt] = (f32x4){0.f, 0.f, 0.f, 0.f};

  const f16* vf0 = vfrag + (size_t)b * 64 * 8192 + lane * 8;

  auto body = [&](int kb, f16 (*pb)[72]) {
    const size_t rt0 = (size_t)((b * SQL + kb) >> 4);
    // --- QK^T: S[16q x 64k]; A-frags lane-linear from kfrag ---
    f32x4 acc[4];
#pragma unroll
    for (int kt = 0; kt < 4; ++kt) {
      f32x4 a = {0.f, 0.f, 0.f, 0.f};
      const f16* kp = kfrag + (rt0 + kt) * 2048 + lane * 8;
#pragma unroll
      for (int c = 0; c < 4; ++c)
        a = mfma16(qa[c], *(const f16x8*)(kp + c * 512), a);
      acc[kt] = a;
    }
    // --- mask + exp + row-sum + transpose staging (wave-private) ---
#pragma unroll
    for (int reg = 0; reg < 4; ++reg) {
      const int row = quad * 4 + reg;
      const int rg = rowbase + row;
      const unsigned long long mb = mbits[(size_t)rg * (SQL / 64) + (kb >> 6)];
#pragma unroll
      for (int kt = 0; kt < 4; ++kt) {
        float sv = acc[kt][reg] * SCALE;
        if ((mb >> (kt * 16 + l15)) & 1ull) sv = -1e30f;
        const float e = __expf(sv);             // masked -> exactly 0
        l[reg] += e;
        pb[row][kt * 16 + l15] = (f16)e;
      }
    }
    // --- spill unnormalized probabilities via pbuf readback ---
    if (SPILLF16) {
      // NOT nontemporal: p16 (134MB) fits L3 -> attnscale reads hit L3
#pragma unroll
      for (int s = 0; s < 2; ++s) {
        const int r  = s * 8 + (lane >> 3);
        const int c0 = (lane & 7) * 8;
        *(f16x8*)(p16 + (size_t)(rowbase + r) * SQL + kb + c0) =
            *(const f16x8*)&pb[r][c0];
      }
    } else {
#pragma unroll
      for (int s = 0; s < 4; ++s) {
        const int r  = s * 4 + (lane >> 4);
        const int c0 = (lane & 15) * 4;
        const f16x4 v = *(const f16x4*)&pb[r][c0];
        f32x4 o;
#pragma unroll
        for (int j = 0; j < 4; ++j) o[j] = (float)v[j];
        __builtin_nontemporal_store(o, (f32x4*)(attn + (size_t)(rowbase + r) * SQL + kb + c0));
      }
    }
    // --- PV: O[16q x 128d] += E[16q x 64k] * V; B-frags lane-linear ---
    const f16* vft = vf0 + (size_t)(kb >> 6) * 8192;
#pragma unroll
    for (int kc2 = 0; kc2 < 2; ++kc2) {
      const f16x8 pa = *(const f16x8*)(&pb[l15][kc2 * 32 + quad * 8]);
#pragma unroll
      for (int dt = 0; dt < 8; ++dt)
        oacc[dt] = mfma16(pa, *(const f16x8*)(vft + dt * 1024 + kc2 * 512), oacc[dt]);
    }
  };

  const int kb0 = kc * (SQL / KSPLIT);             // 512-wide chunk, 8 tiles
  for (int kb = kb0; kb < kb0 + SQL / KSPLIT; kb += 128) {
    body(kb,      pbuf[w][0]);
    body(kb + 64, pbuf[w][1]);
  }

  // per-wave l reduction over the 16 lanes of each quad-group -> direct store
#pragma unroll
  for (int reg = 0; reg < 4; ++reg) {
#pragma unroll
    for (int off = 1; off < 16; off <<= 1) l[reg] += __shfl_xor(l[reg], off);
    if (l15 == 0) lpart[(size_t)kc * NROW + rowbase + quad * 4 + reg] = l[reg];
  }
  // O: each wave owns its rows -> direct store, no reduction
#pragma unroll
  for (int dt = 0; dt < 8; ++dt)
#pragma unroll
    for (int reg = 0; reg < 4; ++reg)
      opart[(size_t)kc * NROW * DIM +
            (size_t)(rowbase + quad * 4 + reg) * DIM + dt * 16 + l15] = oacc[dt][reg];
}

// ---------------------------------------------------------------------------
// Kernel 3: per-row prep, VECTORIZED -- 8 rows/block, f32x4 opart reads.
//   ilrow[r] = 1/sum(lpart[:,r]); out[r][:] = sum(opart[:,r,:]) * ilrow[r].
// ---------------------------------------------------------------------------
__global__ __launch_bounds__(256) void rowprep(const float* __restrict__ lpart,
                                               const float* __restrict__ opart,
                                               float* __restrict__ ilrow,
                                               float* __restrict__ out) {
  const int r  = blockIdx.x * 8 + (threadIdx.x >> 5);
  const int d4 = (threadIdx.x & 31) * 4;
  float s = 0.f;
#pragma unroll
  for (int kc = 0; kc < KSPLIT; ++kc) s += lpart[(size_t)kc * NROW + r];
  const float il = 1.f / s;
  f32x4 o = {0.f, 0.f, 0.f, 0.f};
#pragma unroll
  for (int kc = 0; kc < KSPLIT; ++kc) {
    const f32x4 v = *(const f32x4*)&opart[((size_t)kc * NROW + r) * DIM + d4];
    o[0] += v[0]; o[1] += v[1]; o[2] += v[2]; o[3] += v[3];
  }
  o[0] *= il; o[1] *= il; o[2] *= il; o[3] *= il;
  *(f32x4*)&out[(size_t)r * DIM + d4] = o;
  if ((threadIdx.x & 31) == 0) ilrow[r] = il;
}

// ---------------------------------------------------------------------------
// Kernel 4: pure streaming attn normalization, grid-stride.  p16 reads are
// regular (L3-resident after fused); attn stores nontemporal (never re-read).
// ---------------------------------------------------------------------------
template<int SPILLF16>
__global__ __launch_bounds__(256) void attnscale(const f16* __restrict__ p16,
                                                 const float* __restrict__ ilrow,
                                                 float* __restrict__ attn) {
  const long long stride = (long long)gridDim.x * blockDim.x;
  if (SPILLF16) {
    const long long nchunk = (long long)NROW * SQL / 8;
    const f16x8* src = (const f16x8*)p16;
    f32x4* dst = (f32x4*)attn;
    for (long long c = (long long)blockIdx.x * blockDim.x + threadIdx.x;
         c < nchunk; c += stride) {
      const float il = ilrow[c >> 9];            // 512 f16x8 chunks per row
      const f16x8 v = src[c];
      f32x4 a, b2;
      a[0] = (float)v[0] * il; a[1] = (float)v[1] * il;
      a[2] = (float)v[2] * il; a[3] = (float)v[3] * il;
      b2[0] = (float)v[4] * il; b2[1] = (float)v[5] * il;
      b2[2] = (float)v[6] * il; b2[3] = (float)v[7] * il;
      __builtin_nontemporal_store(a, dst + 2 * c);
      __builtin_nontemporal_store(b2, dst + 2 * c + 1);
    }
  } else {
    const long long nchunk = (long long)NROW * SQL / 4;
    f32x4* dst = (f32x4*)attn;
    for (long long c = (long long)blockIdx.x * blockDim.x + threadIdx.x;
         c < nchunk; c += stride) {
      const float il = ilrow[c >> 10];           // 1024 f32x4 chunks per row
      f32x4 v = dst[c];
      v[0] *= il; v[1] *= il; v[2] *= il; v[3] *= il;
      __builtin_nontemporal_store(v, dst + c);
    }
  }
}

// ---------------------------------------------------------------------------
extern "C" void kernel_launch(void* const* d_in, const int* in_sizes, int n_in,
                              void* d_out, int out_size, void* d_ws, size_t ws_size,
                              hipStream_t stream) {
  const float* inp  = (const float*)d_in[0];
  const float* wk   = (const float*)d_in[1];
  const float* wv   = (const float*)d_in[2];
  const void*  mask = d_in[3];

  float* out  = (float*)d_out;
  float* attn = out + (size_t)NROW * DIM;   // outputs concatenated: out, attn

  char* ws = (char*)d_ws;
  f16* q16   = (f16*)ws;                                 // 4 MB
  f16* kfrag = q16 + (size_t)NROW * DIM;                 // 4 MB (frag order)
  f16* vfrag = kfrag + (size_t)NROW * DIM;               // 4 MB (frag order)
  unsigned long long* mbits =
      (unsigned long long*)(vfrag + (size_t)NROW * DIM); // 8 MB
  char* p = (char*)mbits + (size_t)NROW * (SQL / 8);
  float* lpart = (float*)p; p += (size_t)KSPLIT * NROW * sizeof(float);       // 512 KB
  float* ilrow = (float*)p; p += (size_t)NROW * sizeof(float);                // 64 KB
  float* opart = (float*)p; p += (size_t)KSPLIT * NROW * DIM * sizeof(float); // 67 MB
  f16*   p16   = (f16*)p;                                                      // 134 MB
  const size_t need = (size_t)(p - ws) + (size_t)NROW * SQL * sizeof(f16);
  const bool spill = ws_size >= need;

  prep<<<PREPBLK, 256, 0, stream>>>(inp, wk, wv, mask, q16, kfrag, vfrag,
                                    mbits, NBATCH * SQL * SQL);
  if (spill) {
    fused<1><<<(NROW / 64) * KSPLIT, 256, 0, stream>>>(q16, kfrag, vfrag, mbits,
                                                       lpart, opart, p16, attn);
    rowprep<<<NROW / 8, 256, 0, stream>>>(lpart, opart, ilrow, out);
    attnscale<1><<<4096, 256, 0, stream>>>(p16, ilrow, attn);
  } else {
    fused<0><<<(NROW / 64) * KSPLIT, 256, 0, stream>>>(q16, kfrag, vfrag, mbits,
                                                       lpart, opart, p16, attn);
    rowprep<<<NROW / 8, 256, 0, stream>>>(lpart, opart, ilrow, out);
    attnscale<0><<<4096, 256, 0, stream>>>(p16, ilrow, attn);
  }
}

// Round 9
// 770.360 us; speedup vs baseline: 1.0551x; 1.0551x over previous
//
#include <hip/hip_runtime.h>
#include <hip/hip_fp16.h>
#include <math.h>

#define DIM 128
#define SQL 4096
#define NBATCH 4
#define NROW (NBATCH*SQL)          // 16384 total rows
#define SCALE 0.08838834764831845f // 1/sqrt(128)
#define KSPLIT 8                   // K-range split across blocks

typedef _Float16 f16;
typedef _Float16 f16x4 __attribute__((ext_vector_type(4)));
typedef _Float16 f16x8 __attribute__((ext_vector_type(8)));
typedef float f32x4 __attribute__((ext_vector_type(4)));

__device__ __forceinline__ f32x4 mfma16(f16x8 a, f16x8 b, f32x4 c) {
  return __builtin_amdgcn_mfma_f32_16x16x32_f16(a, b, c, 0, 0, 0);
}

// ---------------------------------------------------------------------------
// Kernel 1: pack mask to 1 bit/element, VECTORIZED (uint4 = 16B/lane loads).
// Runtime-detect int32 vs byte layout (64 random 0/1 BYTES viewed as u32 are
// never all <=1; int32 0/1 always).  Byte-nonzero via carry trick.
// ---------------------------------------------------------------------------
__global__ __launch_bounds__(256) void maskpack(const void* __restrict__ mask,
                                                unsigned long long* __restrict__ mbits,
                                                int n) {
  __shared__ int s_is32;
  if (threadIdx.x == 0) {
    const unsigned int* w = (const unsigned int*)mask;
    int ok = 1;
    for (int i = 0; i < 64; ++i) ok &= (w[i] <= 1u);
    s_is32 = ok;
  }
  __syncthreads();
  const int t = threadIdx.x;
  const int stride = gridDim.x * blockDim.x;
  const uint4* mv = (const uint4*)mask;

  if (s_is32) {
    const int nvec = n >> 2;                    // 16M
    for (int i = blockIdx.x * blockDim.x + t; i < nvec; i += stride) {
      const uint4 v = mv[i];
      const unsigned int nib = (v.x != 0u) | ((v.y != 0u) << 1) |
                               ((v.z != 0u) << 2) | ((v.w != 0u) << 3);
      unsigned long long bits = (unsigned long long)nib << ((i & 15) * 4);
      bits |= __shfl_xor(bits, 1);
      bits |= __shfl_xor(bits, 2);
      bits |= __shfl_xor(bits, 4);
      bits |= __shfl_xor(bits, 8);
      if ((t & 15) == 0) mbits[i >> 4] = bits;   // word = (i*4)>>6
    }
  } else {
    const int nvec = n >> 4;                    // 4M
    for (int i = blockIdx.x * blockDim.x + t; i < nvec; i += stride) {
      const uint4 v = mv[i];
      const unsigned int M = 0x01020408u;
      unsigned int x;
      x = ((v.x | ((v.x & 0x7F7F7F7Fu) + 0x7F7F7F7Fu)) >> 7) & 0x01010101u;
      const unsigned int n0 = ((x * M) >> 24) & 0xFu;
      x = ((v.y | ((v.y & 0x7F7F7F7Fu) + 0x7F7F7F7Fu)) >> 7) & 0x01010101u;
      const unsigned int n1 = ((x * M) >> 24) & 0xFu;
      x = ((v.z | ((v.z & 0x7F7F7F7Fu) + 0x7F7F7F7Fu)) >> 7) & 0x01010101u;
      const unsigned int n2 = ((x * M) >> 24) & 0xFu;
      x = ((v.w | ((v.w & 0x7F7F7F7Fu) + 0x7F7F7F7Fu)) >> 7) & 0x01010101u;
      const unsigned int n3 = ((x * M) >> 24) & 0xFu;
      const unsigned int b16 = n0 | (n1 << 4) | (n2 << 8) | (n3 << 12);
      unsigned long long bits = (unsigned long long)b16 << ((i & 3) * 16);
      bits |= __shfl_xor(bits, 1);
      bits |= __shfl_xor(bits, 2);
      if ((t & 3) == 0) mbits[i >> 2] = bits;    // word = (i*16)>>6
    }
  }
}

// ---------------------------------------------------------------------------
// Kernel 2: projections K = inp*Wk^T, V = inp*Wv^T (fp32 math), emit
//   q16[row][d]  = fp16(inp)
//   kfrag        = fp16(K) in MFMA A-frag order [rt][c][quad][l15][8] (4KB/t)
//   vfrag        = fp16(V) in MFMA B-frag order [kt64][dt][kc2][q][l15][8]
// so every hot-loop fragment load in `fused` is base + lane*16B.
// ---------------------------------------------------------------------------
__global__ __launch_bounds__(256) void proj(const float* __restrict__ inp,
                                            const float* __restrict__ wk,
                                            const float* __restrict__ wv,
                                            f16* __restrict__ q16,
                                            f16* __restrict__ kfrag,
                                            f16* __restrict__ vfrag) {
  __shared__ float s_in[16][DIM];                 // 8 KB
  __shared__ __align__(16) f16 s_vt[DIM][16];     // 4 KB V^T staging
  __shared__ __align__(16) f16 s_kf[2048];        // 4 KB K fragment staging
  const int rowbase = blockIdx.x * 16;
  const int t = threadIdx.x;
  const int e = t & 127;
  const int half_ = t >> 7;

  for (int r = half_; r < 16; r += 2)
    s_in[r][e] = inp[(size_t)(rowbase + r) * DIM + e];
  __syncthreads();

  float ak[8], av[8];
#pragma unroll
  for (int i = 0; i < 8; ++i) { ak[i] = 0.f; av[i] = 0.f; }

  for (int d0 = 0; d0 < DIM; d0 += 8) {
    float wkl[8], wvl[8];
#pragma unroll
    for (int j = 0; j < 8; ++j) {
      wkl[j] = wk[(size_t)e * DIM + d0 + j];
      wvl[j] = wv[(size_t)e * DIM + d0 + j];
    }
#pragma unroll
    for (int i = 0; i < 8; ++i) {
      const int r = half_ * 8 + i;
#pragma unroll
      for (int j = 0; j < 8; ++j) {
        const float x = s_in[r][d0 + j];
        ak[i] += x * wkl[j];
        av[i] += x * wvl[j];
      }
    }
  }

  // col e decomposes as c=e>>5 (A-reg), quad=(e>>3)&3, j=e&7
  const int koff = (e >> 5) * 512 + ((e >> 3) & 3) * 128 + (e & 7);
#pragma unroll
  for (int i = 0; i < 8; ++i) {
    const int r = half_ * 8 + i;                  // l15 = row within tile
    s_kf[koff + r * 8] = (f16)ak[i];
    q16[(size_t)(rowbase + r) * DIM + e] = (f16)s_in[r][e];
    s_vt[e][r] = (f16)av[i];
  }
  __syncthreads();

  // kfrag copyout: 2048 halfs contiguous, 16B per thread
  *(f16x8*)(kfrag + ((size_t)(rowbase >> 4)) * 2048 + t * 8) =
      *(const f16x8*)&s_kf[t * 8];

  // vfrag copyout: 16 seq-rows -> (kc2,qh) slot of the 64-row tile
  const int b    = rowbase / SQL;
  const int srow = rowbase % SQL;
  const int m    = (srow >> 4) & 3;
  const int kc2_ = m >> 1, qh = m & 1;
  const int dt_ = t >> 5, h8 = (t >> 4) & 1, l15_ = t & 15;
  const f16x8 vv = *(const f16x8*)&s_vt[dt_ * 16 + l15_][h8 * 8];
  *(f16x8*)(vfrag + ((size_t)b * 64 + (srow >> 6)) * 8192 +
            dt_ * 1024 + kc2_ * 512 + (2 * qh + h8) * 128 + l15_ * 8) = vv;
}

// ---------------------------------------------------------------------------
// Kernel 3: single pass over K (ROUND-6 structure: single body, KSPLIT=8,
// grid 2048, NT spill, LDS 9.2 KB -- the 46%-occupancy config).
// ONE change: mbits REGISTER DOUBLE-BUFFER.  The 4 mbits words per tile are
// the only latency-critical scalar loads in the exp path (consumed right
// after issue).  Prologue loads tile 0; each body issues tile t+1's loads
// FIRST (they hide under QK MFMA), consumes tile t's pre-loaded values.
// ---------------------------------------------------------------------------
template<int SPILLF16>
__global__ __launch_bounds__(256) void fused(const f16* __restrict__ q16,
                                             const f16* __restrict__ kfrag,
                                             const f16* __restrict__ vfrag,
                                             const unsigned long long* __restrict__ mbits,
                                             float* __restrict__ lpart,
                                             float* __restrict__ opart,
                                             f16* __restrict__ p16,
                                             float* __restrict__ attn) {
  __shared__ __align__(16) f16 pbuf[4][16][72];   // 9.2 KB, wave-private slices
  const int kc      = blockIdx.x & (KSPLIT - 1);
  const int blkrow  = (blockIdx.x >> 3) * 64;     // 64 q-rows per block
  const int b = blkrow / SQL;
  const int lane = threadIdx.x & 63;
  const int w = threadIdx.x >> 6;
  const int rowbase = blkrow + w * 16;            // this wave's 16 rows
  const int l15 = lane & 15, quad = lane >> 4;

  f16x8 qa[4];
  {
    const f16* qp = q16 + (size_t)(rowbase + l15) * DIM + quad * 8;
#pragma unroll
    for (int c = 0; c < 4; ++c) qa[c] = *(const f16x8*)(qp + c * 32);
  }

  float l[4];
#pragma unroll
  for (int r = 0; r < 4; ++r) l[r] = 0.f;

  f32x4 oacc[8];
#pragma unroll
  for (int dt = 0; dt < 8; ++dt) oacc[dt] = (f32x4){0.f, 0.f, 0.f, 0.f};

  const f16* vf0 = vfrag + (size_t)b * 64 * 8192 + lane * 8;

  const int kb0 = kc * (SQL / KSPLIT);            // 512-wide chunk, 8 tiles
  const int kbend = kb0 + SQL / KSPLIT;

  // mbits register double-buffer: base pointers + prologue load of tile 0
  const unsigned long long* mrow[4];
#pragma unroll
  for (int reg = 0; reg < 4; ++reg)
    mrow[reg] = mbits + (size_t)(rowbase + quad * 4 + reg) * (SQL / 64);
  unsigned long long mb_cur[4];
#pragma unroll
  for (int reg = 0; reg < 4; ++reg) mb_cur[reg] = mrow[reg][kb0 >> 6];

  for (int kb = kb0; kb < kbend; kb += 64) {
    // --- issue NEXT tile's mask loads first (hide under QK MFMA) ---
    unsigned long long mb_nxt[4];
    const int wnext = (kb + 64 < kbend) ? ((kb + 64) >> 6) : (kb >> 6);
#pragma unroll
    for (int reg = 0; reg < 4; ++reg) mb_nxt[reg] = mrow[reg][wnext];

    const size_t rt0 = (size_t)((b * SQL + kb) >> 4);
    // --- QK^T: S[16q x 64k]; A-frags lane-linear from kfrag ---
    f32x4 acc[4];
#pragma unroll
    for (int kt = 0; kt < 4; ++kt) {
      f32x4 a = {0.f, 0.f, 0.f, 0.f};
      const f16* kp = kfrag + (rt0 + kt) * 2048 + lane * 8;
#pragma unroll
      for (int c = 0; c < 4; ++c)
        a = mfma16(qa[c], *(const f16x8*)(kp + c * 512), a);
      acc[kt] = a;
    }
    // --- mask + exp + row-sum + transpose staging (wave-private) ---
#pragma unroll
    for (int reg = 0; reg < 4; ++reg) {
      const int row = quad * 4 + reg;
      const unsigned long long mb = mb_cur[reg];
#pragma unroll
      for (int kt = 0; kt < 4; ++kt) {
        float sv = acc[kt][reg] * SCALE;
        if ((mb >> (kt * 16 + l15)) & 1ull) sv = -1e30f;
        const float e = __expf(sv);             // masked -> exactly 0
        l[reg] += e;
        pbuf[w][row][kt * 16 + l15] = (f16)e;
      }
    }
    // --- spill unnormalized probabilities, VECTORIZED via pbuf readback ---
    if (SPILLF16) {
#pragma unroll
      for (int s = 0; s < 2; ++s) {
        const int r  = s * 8 + (lane >> 3);
        const int c0 = (lane & 7) * 8;
        const f16x8 v = *(const f16x8*)&pbuf[w][r][c0];
        __builtin_nontemporal_store(v, (f16x8*)(p16 + (size_t)(rowbase + r) * SQL + kb + c0));
      }
    } else {
#pragma unroll
      for (int s = 0; s < 4; ++s) {
        const int r  = s * 4 + (lane >> 4);
        const int c0 = (lane & 15) * 4;
        const f16x4 v = *(const f16x4*)&pbuf[w][r][c0];
        f32x4 o;
#pragma unroll
        for (int j = 0; j < 4; ++j) o[j] = (float)v[j];
        __builtin_nontemporal_store(o, (f32x4*)(attn + (size_t)(rowbase + r) * SQL + kb + c0));
      }
    }
    // --- PV: O[16q x 128d] += E[16q x 64k] * V; B-frags lane-linear ---
    const f16* vft = vf0 + (size_t)(kb >> 6) * 8192;
#pragma unroll
    for (int kc2 = 0; kc2 < 2; ++kc2) {
      const f16x8 pa = *(const f16x8*)(&pbuf[w][l15][kc2 * 32 + quad * 8]);
#pragma unroll
      for (int dt = 0; dt < 8; ++dt)
        oacc[dt] = mfma16(pa, *(const f16x8*)(vft + dt * 1024 + kc2 * 512), oacc[dt]);
    }
    // rotate mask buffer
#pragma unroll
    for (int reg = 0; reg < 4; ++reg) mb_cur[reg] = mb_nxt[reg];
  }

  // per-wave l reduction over the 16 lanes of each quad-group -> direct store
#pragma unroll
  for (int reg = 0; reg < 4; ++reg) {
#pragma unroll
    for (int off = 1; off < 16; off <<= 1) l[reg] += __shfl_xor(l[reg], off);
    if (l15 == 0) lpart[(size_t)kc * NROW + rowbase + quad * 4 + reg] = l[reg];
  }
  // O: each wave owns its rows -> direct store, no reduction
#pragma unroll
  for (int dt = 0; dt < 8; ++dt)
#pragma unroll
    for (int reg = 0; reg < 4; ++reg)
      opart[(size_t)kc * NROW * DIM +
            (size_t)(rowbase + quad * 4 + reg) * DIM + dt * 16 + l15] = oacc[dt][reg];
}

// ---------------------------------------------------------------------------
// Kernel 4a: per-row prep, VECTORIZED -- 8 rows/block, f32x4 opart reads.
//   ilrow[r] = 1/sum(lpart[:,r]); out[r][:] = sum(opart[:,r,:]) * ilrow[r].
// ---------------------------------------------------------------------------
__global__ __launch_bounds__(256) void rowprep(const float* __restrict__ lpart,
                                               const float* __restrict__ opart,
                                               float* __restrict__ ilrow,
                                               float* __restrict__ out) {
  const int r  = blockIdx.x * 8 + (threadIdx.x >> 5);
  const int d4 = (threadIdx.x & 31) * 4;
  float s = 0.f;
#pragma unroll
  for (int kc = 0; kc < KSPLIT; ++kc) s += lpart[(size_t)kc * NROW + r];
  const float il = 1.f / s;
  f32x4 o = {0.f, 0.f, 0.f, 0.f};
#pragma unroll
  for (int kc = 0; kc < KSPLIT; ++kc) {
    const f32x4 v = *(const f32x4*)&opart[((size_t)kc * NROW + r) * DIM + d4];
    o[0] += v[0]; o[1] += v[1]; o[2] += v[2]; o[3] += v[3];
  }
  o[0] *= il; o[1] *= il; o[2] *= il; o[3] *= il;
  *(f32x4*)&out[(size_t)r * DIM + d4] = o;
  if ((threadIdx.x & 31) == 0) ilrow[r] = il;
}

// ---------------------------------------------------------------------------
// Kernel 4b: pure streaming attn normalization, grid-stride.
// ---------------------------------------------------------------------------
template<int SPILLF16>
__global__ __launch_bounds__(256) void attnscale(const f16* __restrict__ p16,
                                                 const float* __restrict__ ilrow,
                                                 float* __restrict__ attn) {
  const long long stride = (long long)gridDim.x * blockDim.x;
  if (SPILLF16) {
    const long long nchunk = (long long)NROW * SQL / 8;
    const f16x8* src = (const f16x8*)p16;
    f32x4* dst = (f32x4*)attn;
    for (long long c = (long long)blockIdx.x * blockDim.x + threadIdx.x;
         c < nchunk; c += stride) {
      const float il = ilrow[c >> 9];            // 512 f16x8 chunks per row
      const f16x8 v = __builtin_nontemporal_load(src + c);
      f32x4 a, b2;
      a[0] = (float)v[0] * il; a[1] = (float)v[1] * il;
      a[2] = (float)v[2] * il; a[3] = (float)v[3] * il;
      b2[0] = (float)v[4] * il; b2[1] = (float)v[5] * il;
      b2[2] = (float)v[6] * il; b2[3] = (float)v[7] * il;
      __builtin_nontemporal_store(a, dst + 2 * c);
      __builtin_nontemporal_store(b2, dst + 2 * c + 1);
    }
  } else {
    const long long nchunk = (long long)NROW * SQL / 4;
    f32x4* dst = (f32x4*)attn;
    for (long long c = (long long)blockIdx.x * blockDim.x + threadIdx.x;
         c < nchunk; c += stride) {
      const float il = ilrow[c >> 10];           // 1024 f32x4 chunks per row
      f32x4 v = dst[c];
      v[0] *= il; v[1] *= il; v[2] *= il; v[3] *= il;
      __builtin_nontemporal_store(v, dst + c);
    }
  }
}

// ---------------------------------------------------------------------------
extern "C" void kernel_launch(void* const* d_in, const int* in_sizes, int n_in,
                              void* d_out, int out_size, void* d_ws, size_t ws_size,
                              hipStream_t stream) {
  const float* inp  = (const float*)d_in[0];
  const float* wk   = (const float*)d_in[1];
  const float* wv   = (const float*)d_in[2];
  const void*  mask = d_in[3];

  float* out  = (float*)d_out;
  float* attn = out + (size_t)NROW * DIM;   // outputs concatenated: out, attn

  char* ws = (char*)d_ws;
  f16* q16   = (f16*)ws;                                 // 4 MB
  f16* kfrag = q16 + (size_t)NROW * DIM;                 // 4 MB (frag order)
  f16* vfrag = kfrag + (size_t)NROW * DIM;               // 4 MB (frag order)
  unsigned long long* mbits =
      (unsigned long long*)(vfrag + (size_t)NROW * DIM); // 8 MB
  char* p = (char*)mbits + (size_t)NROW * (SQL / 8);
  float* lpart = (float*)p; p += (size_t)KSPLIT * NROW * sizeof(float);       // 512 KB
  float* ilrow = (float*)p; p += (size_t)NROW * sizeof(float);                // 64 KB
  float* opart = (float*)p; p += (size_t)KSPLIT * NROW * DIM * sizeof(float); // 67 MB
  f16*   p16   = (f16*)p;                                                      // 134 MB
  const size_t need = (size_t)(p - ws) + (size_t)NROW * SQL * sizeof(f16);
  const bool spill = ws_size >= need;

  maskpack<<<8192, 256, 0, stream>>>(mask, mbits, NBATCH * SQL * SQL);
  proj<<<NROW / 16, 256, 0, stream>>>(inp, wk, wv, q16, kfrag, vfrag);
  if (spill) {
    fused<1><<<(NROW / 64) * KSPLIT, 256, 0, stream>>>(q16, kfrag, vfrag, mbits,
                                                       lpart, opart, p16, attn);
    rowprep<<<NROW / 8, 256, 0, stream>>>(lpart, opart, ilrow, out);
    attnscale<1><<<4096, 256, 0, stream>>>(p16, ilrow, attn);
  } else {
    fused<0><<<(NROW / 64) * KSPLIT, 256, 0, stream>>>(q16, kfrag, vfrag, mbits,
                                                       lpart, opart, p16, attn);
    rowprep<<<NROW / 8, 256, 0, stream>>>(lpart, opart, ilrow, out);
    attnscale<0><<<4096, 256, 0, stream>>>(p16, ilrow, attn);
  }
}

// Round 11
// 610.453 us; speedup vs baseline: 1.3314x; 1.2619x over previous
//
#include <hip/hip_runtime.h>
#include <hip/hip_fp16.h>
#include <math.h>

#define DIM 128
#define SQL 4096
#define NBATCH 4
#define NROW (NBATCH*SQL)          // 16384 total rows
#define SCALE 0.08838834764831845f // 1/sqrt(128)
#define KSPLIT 8                   // K-range split across blocks

typedef _Float16 f16;
typedef _Float16 f16x4 __attribute__((ext_vector_type(4)));
typedef _Float16 f16x8 __attribute__((ext_vector_type(8)));
typedef float f32x4 __attribute__((ext_vector_type(4)));
typedef unsigned int u32x4 __attribute__((ext_vector_type(4)));  // NT-load-able

__device__ __forceinline__ f32x4 mfma16(f16x8 a, f16x8 b, f32x4 c) {
  return __builtin_amdgcn_mfma_f32_16x16x32_f16(a, b, c, 0, 0, 0);
}

// ---------------------------------------------------------------------------
// Kernel 1: pack mask to 1 bit/element, VECTORIZED (16B/lane NT loads --
// read-once stream, keep L2 clean for kfrag/vfrag).  Runtime-detect int32 vs
// byte layout (64 random 0/1 BYTES viewed as u32 are never all <=1; int32
// 0/1 always).  Byte-nonzero via carry trick (`!=0` semantics).
// NOTE: use clang ext_vector u32x4, NOT HIP's uint4 class --
// __builtin_nontemporal_load rejects HIP_vector_type (round-10 compile fail).
// ---------------------------------------------------------------------------
__global__ __launch_bounds__(256) void maskpack(const void* __restrict__ mask,
                                                unsigned long long* __restrict__ mbits,
                                                int n) {
  __shared__ int s_is32;
  if (threadIdx.x == 0) {
    const unsigned int* w = (const unsigned int*)mask;
    int ok = 1;
    for (int i = 0; i < 64; ++i) ok &= (w[i] <= 1u);
    s_is32 = ok;
  }
  __syncthreads();
  const int t = threadIdx.x;
  const int stride = gridDim.x * blockDim.x;
  const u32x4* mv = (const u32x4*)mask;

  if (s_is32) {
    const int nvec = n >> 2;                    // 16M
    for (int i = blockIdx.x * blockDim.x + t; i < nvec; i += stride) {
      const u32x4 v = __builtin_nontemporal_load(mv + i);
      const unsigned int nib = (v[0] != 0u) | ((v[1] != 0u) << 1) |
                               ((v[2] != 0u) << 2) | ((v[3] != 0u) << 3);
      unsigned long long bits = (unsigned long long)nib << ((i & 15) * 4);
      bits |= __shfl_xor(bits, 1);
      bits |= __shfl_xor(bits, 2);
      bits |= __shfl_xor(bits, 4);
      bits |= __shfl_xor(bits, 8);
      if ((t & 15) == 0) mbits[i >> 4] = bits;   // word = (i*4)>>6
    }
  } else {
    const int nvec = n >> 4;                    // 4M
    for (int i = blockIdx.x * blockDim.x + t; i < nvec; i += stride) {
      const u32x4 v = __builtin_nontemporal_load(mv + i);
      const unsigned int M = 0x01020408u;
      unsigned int x;
      x = ((v[0] | ((v[0] & 0x7F7F7F7Fu) + 0x7F7F7F7Fu)) >> 7) & 0x01010101u;
      const unsigned int n0 = ((x * M) >> 24) & 0xFu;
      x = ((v[1] | ((v[1] & 0x7F7F7F7Fu) + 0x7F7F7F7Fu)) >> 7) & 0x01010101u;
      const unsigned int n1 = ((x * M) >> 24) & 0xFu;
      x = ((v[2] | ((v[2] & 0x7F7F7F7Fu) + 0x7F7F7F7Fu)) >> 7) & 0x01010101u;
      const unsigned int n2 = ((x * M) >> 24) & 0xFu;
      x = ((v[3] | ((v[3] & 0x7F7F7F7Fu) + 0x7F7F7F7Fu)) >> 7) & 0x01010101u;
      const unsigned int n3 = ((x * M) >> 24) & 0xFu;
      const unsigned int b16 = n0 | (n1 << 4) | (n2 << 8) | (n3 << 12);
      unsigned long long bits = (unsigned long long)b16 << ((i & 3) * 16);
      bits |= __shfl_xor(bits, 1);
      bits |= __shfl_xor(bits, 2);
      if ((t & 3) == 0) mbits[i >> 2] = bits;    // word = (i*16)>>6
    }
  }
}

// ---------------------------------------------------------------------------
// Kernel 2: projections K = inp*Wk^T, V = inp*Wv^T (fp32 math), emit
//   q16[row][d]  = fp16(inp)
//   kfrag        = fp16(K) in MFMA A-frag order [rt][c][quad][l15][8] (4KB/t)
//   vfrag        = fp16(V) in MFMA B-frag order [kt64][dt][kc2][q][l15][8]
// so every hot-loop fragment load in `fused` is base + lane*16B.
// (EXACT round-6 kernel -- the 650us config.)
// ---------------------------------------------------------------------------
__global__ __launch_bounds__(256) void proj(const float* __restrict__ inp,
                                            const float* __restrict__ wk,
                                            const float* __restrict__ wv,
                                            f16* __restrict__ q16,
                                            f16* __restrict__ kfrag,
                                            f16* __restrict__ vfrag) {
  __shared__ float s_in[16][DIM];                 // 8 KB
  __shared__ __align__(16) f16 s_vt[DIM][16];     // 4 KB V^T staging
  __shared__ __align__(16) f16 s_kf[2048];        // 4 KB K fragment staging
  const int rowbase = blockIdx.x * 16;
  const int t = threadIdx.x;
  const int e = t & 127;
  const int half_ = t >> 7;

  for (int r = half_; r < 16; r += 2)
    s_in[r][e] = inp[(size_t)(rowbase + r) * DIM + e];
  __syncthreads();

  float ak[8], av[8];
#pragma unroll
  for (int i = 0; i < 8; ++i) { ak[i] = 0.f; av[i] = 0.f; }

  for (int d0 = 0; d0 < DIM; d0 += 8) {
    float wkl[8], wvl[8];
#pragma unroll
    for (int j = 0; j < 8; ++j) {
      wkl[j] = wk[(size_t)e * DIM + d0 + j];
      wvl[j] = wv[(size_t)e * DIM + d0 + j];
    }
#pragma unroll
    for (int i = 0; i < 8; ++i) {
      const int r = half_ * 8 + i;
#pragma unroll
      for (int j = 0; j < 8; ++j) {
        const float x = s_in[r][d0 + j];
        ak[i] += x * wkl[j];
        av[i] += x * wvl[j];
      }
    }
  }

  // col e decomposes as c=e>>5 (A-reg), quad=(e>>3)&3, j=e&7
  const int koff = (e >> 5) * 512 + ((e >> 3) & 3) * 128 + (e & 7);
#pragma unroll
  for (int i = 0; i < 8; ++i) {
    const int r = half_ * 8 + i;                  // l15 = row within tile
    s_kf[koff + r * 8] = (f16)ak[i];
    q16[(size_t)(rowbase + r) * DIM + e] = (f16)s_in[r][e];
    s_vt[e][r] = (f16)av[i];
  }
  __syncthreads();

  // kfrag copyout: 2048 halfs contiguous, 16B per thread
  *(f16x8*)(kfrag + ((size_t)(rowbase >> 4)) * 2048 + t * 8) =
      *(const f16x8*)&s_kf[t * 8];

  // vfrag copyout: 16 seq-rows -> (kc2,qh) slot of the 64-row tile
  const int b    = rowbase / SQL;
  const int srow = rowbase % SQL;
  const int m    = (srow >> 4) & 3;
  const int kc2_ = m >> 1, qh = m & 1;
  const int dt_ = t >> 5, h8 = (t >> 4) & 1, l15_ = t & 15;
  const f16x8 vv = *(const f16x8*)&s_vt[dt_ * 16 + l15_][h8 * 8];
  *(f16x8*)(vfrag + ((size_t)b * 64 + (srow >> 6)) * 8192 +
            dt_ * 1024 + kc2_ * 512 + (2 * qh + h8) * 128 + l15_ * 8) = vv;
}

// ---------------------------------------------------------------------------
// Kernel 3: single pass over K.  EXACT round-6 kernel (650us config):
// wave owns 16 q-rows, block = 64 rows, KSPLIT=8 (grid 2048), zero
// barriers, LDS 9.2 KB, VGPR 60 -> 8 waves/SIMD bin.
// DO NOT add registers: VGPR>64 halves occupancy (round-9 lesson: +8 VGPR
// for mask prefetch -> occ 46->30%, dur 165->223us).
// ---------------------------------------------------------------------------
template<int SPILLF16>
__global__ __launch_bounds__(256) void fused(const f16* __restrict__ q16,
                                             const f16* __restrict__ kfrag,
                                             const f16* __restrict__ vfrag,
                                             const unsigned long long* __restrict__ mbits,
                                             float* __restrict__ lpart,
                                             float* __restrict__ opart,
                                             f16* __restrict__ p16,
                                             float* __restrict__ attn) {
  __shared__ __align__(16) f16 pbuf[4][16][72];   // 9.2 KB, wave-private slices
  const int kc      = blockIdx.x & (KSPLIT - 1);
  const int blkrow  = (blockIdx.x >> 3) * 64;     // 64 q-rows per block
  const int b = blkrow / SQL;
  const int lane = threadIdx.x & 63;
  const int w = threadIdx.x >> 6;
  const int rowbase = blkrow + w * 16;            // this wave's 16 rows
  const int l15 = lane & 15, quad = lane >> 4;

  f16x8 qa[4];
  {
    const f16* qp = q16 + (size_t)(rowbase + l15) * DIM + quad * 8;
#pragma unroll
    for (int c = 0; c < 4; ++c) qa[c] = *(const f16x8*)(qp + c * 32);
  }

  float l[4];
#pragma unroll
  for (int r = 0; r < 4; ++r) l[r] = 0.f;

  f32x4 oacc[8];
#pragma unroll
  for (int dt = 0; dt < 8; ++dt) oacc[dt] = (f32x4){0.f, 0.f, 0.f, 0.f};

  const f16* vf0 = vfrag + (size_t)b * 64 * 8192 + lane * 8;

  const int kb0 = kc * (SQL / KSPLIT);            // 512-wide chunk, 8 tiles
  for (int kb = kb0; kb < kb0 + SQL / KSPLIT; kb += 64) {
    const size_t rt0 = (size_t)((b * SQL + kb) >> 4);
    // --- QK^T: S[16q x 64k]; A-frags lane-linear from kfrag ---
    f32x4 acc[4];
#pragma unroll
    for (int kt = 0; kt < 4; ++kt) {
      f32x4 a = {0.f, 0.f, 0.f, 0.f};
      const f16* kp = kfrag + (rt0 + kt) * 2048 + lane * 8;
#pragma unroll
      for (int c = 0; c < 4; ++c)
        a = mfma16(qa[c], *(const f16x8*)(kp + c * 512), a);
      acc[kt] = a;
    }
    // --- mask + exp + row-sum + transpose staging (wave-private) ---
#pragma unroll
    for (int reg = 0; reg < 4; ++reg) {
      const int row = quad * 4 + reg;
      const int rg = rowbase + row;
      const unsigned long long mb = mbits[(size_t)rg * (SQL / 64) + (kb >> 6)];
#pragma unroll
      for (int kt = 0; kt < 4; ++kt) {
        float sv = acc[kt][reg] * SCALE;
        if ((mb >> (kt * 16 + l15)) & 1ull) sv = -1e30f;
        const float e = __expf(sv);             // masked -> exactly 0
        l[reg] += e;
        pbuf[w][row][kt * 16 + l15] = (f16)e;
      }
    }
    // --- spill unnormalized probabilities, VECTORIZED via pbuf readback ---
    if (SPILLF16) {
#pragma unroll
      for (int s = 0; s < 2; ++s) {
        const int r  = s * 8 + (lane >> 3);
        const int c0 = (lane & 7) * 8;
        const f16x8 v = *(const f16x8*)&pbuf[w][r][c0];
        __builtin_nontemporal_store(v, (f16x8*)(p16 + (size_t)(rowbase + r) * SQL + kb + c0));
      }
    } else {
#pragma unroll
      for (int s = 0; s < 4; ++s) {
        const int r  = s * 4 + (lane >> 4);
        const int c0 = (lane & 15) * 4;
        const f16x4 v = *(const f16x4*)&pbuf[w][r][c0];
        f32x4 o;
#pragma unroll
        for (int j = 0; j < 4; ++j) o[j] = (float)v[j];
        __builtin_nontemporal_store(o, (f32x4*)(attn + (size_t)(rowbase + r) * SQL + kb + c0));
      }
    }
    // --- PV: O[16q x 128d] += E[16q x 64k] * V; B-frags lane-linear ---
    const f16* vft = vf0 + (size_t)(kb >> 6) * 8192;
#pragma unroll
    for (int kc2 = 0; kc2 < 2; ++kc2) {
      const f16x8 pa = *(const f16x8*)(&pbuf[w][l15][kc2 * 32 + quad * 8]);
#pragma unroll
      for (int dt = 0; dt < 8; ++dt)
        oacc[dt] = mfma16(pa, *(const f16x8*)(vft + dt * 1024 + kc2 * 512), oacc[dt]);
    }
  }

  // per-wave l reduction over the 16 lanes of each quad-group -> direct store
#pragma unroll
  for (int reg = 0; reg < 4; ++reg) {
#pragma unroll
    for (int off = 1; off < 16; off <<= 1) l[reg] += __shfl_xor(l[reg], off);
    if (l15 == 0) lpart[(size_t)kc * NROW + rowbase + quad * 4 + reg] = l[reg];
  }
  // O: each wave owns its rows -> direct store, no reduction
#pragma unroll
  for (int dt = 0; dt < 8; ++dt)
#pragma unroll
    for (int reg = 0; reg < 4; ++reg)
      opart[(size_t)kc * NROW * DIM +
            (size_t)(rowbase + quad * 4 + reg) * DIM + dt * 16 + l15] = oacc[dt][reg];
}

// ---------------------------------------------------------------------------
// Kernel 4: finalize = rowprep + attnscale MERGED, one block per row.
//   il = 1/sum(lpart[:,r])  (8 broadcast loads, all threads redundant)
//   attn[r][:] = f32(p16[r][:]) * il   (NT load + NT store, 2 chunks/thread)
//   out[r][:]  = sum(opart[:,r,:]) * il  (threads 0..127)
// ---------------------------------------------------------------------------
template<int SPILLF16>
__global__ __launch_bounds__(256) void finalize(const f16* __restrict__ p16,
                                                const float* __restrict__ lpart,
                                                const float* __restrict__ opart,
                                                float* __restrict__ attn,
                                                float* __restrict__ out) {
  const int r = blockIdx.x;
  const int t = threadIdx.x;
  float s = 0.f;
#pragma unroll
  for (int kc = 0; kc < KSPLIT; ++kc) s += lpart[(size_t)kc * NROW + r];
  const float il = 1.f / s;

  if (SPILLF16) {
    const f16x8* src = (const f16x8*)(p16 + (size_t)r * SQL);
    f32x4* dst = (f32x4*)(attn + (size_t)r * SQL);
#pragma unroll
    for (int c = t; c < SQL / 8; c += 256) {   // 2 iterations
      const f16x8 v = __builtin_nontemporal_load(src + c);
      f32x4 a, b2;
      a[0] = (float)v[0] * il; a[1] = (float)v[1] * il;
      a[2] = (float)v[2] * il; a[3] = (float)v[3] * il;
      b2[0] = (float)v[4] * il; b2[1] = (float)v[5] * il;
      b2[2] = (float)v[6] * il; b2[3] = (float)v[7] * il;
      __builtin_nontemporal_store(a, dst + 2 * c);
      __builtin_nontemporal_store(b2, dst + 2 * c + 1);
    }
  } else {
    f32x4* dst = (f32x4*)(attn + (size_t)r * SQL);
#pragma unroll
    for (int c = t; c < SQL / 4; c += 256) {   // 4 iterations, same-addr RMW
      f32x4 v = dst[c];
      v[0] *= il; v[1] *= il; v[2] *= il; v[3] *= il;
      __builtin_nontemporal_store(v, dst + c);
    }
  }
  if (t < DIM) {
    float o = 0.f;
#pragma unroll
    for (int kc = 0; kc < KSPLIT; ++kc)
      o += opart[((size_t)kc * NROW + r) * DIM + t];
    out[(size_t)r * DIM + t] = o * il;
  }
}

// ---------------------------------------------------------------------------
extern "C" void kernel_launch(void* const* d_in, const int* in_sizes, int n_in,
                              void* d_out, int out_size, void* d_ws, size_t ws_size,
                              hipStream_t stream) {
  const float* inp  = (const float*)d_in[0];
  const float* wk   = (const float*)d_in[1];
  const float* wv   = (const float*)d_in[2];
  const void*  mask = d_in[3];

  float* out  = (float*)d_out;
  float* attn = out + (size_t)NROW * DIM;   // outputs concatenated: out, attn

  char* ws = (char*)d_ws;
  f16* q16   = (f16*)ws;                                 // 4 MB
  f16* kfrag = q16 + (size_t)NROW * DIM;                 // 4 MB (frag order)
  f16* vfrag = kfrag + (size_t)NROW * DIM;               // 4 MB (frag order)
  unsigned long long* mbits =
      (unsigned long long*)(vfrag + (size_t)NROW * DIM); // 8 MB
  char* p = (char*)mbits + (size_t)NROW * (SQL / 8);
  float* lpart = (float*)p; p += (size_t)KSPLIT * NROW * sizeof(float);       // 512 KB
  float* opart = (float*)p; p += (size_t)KSPLIT * NROW * DIM * sizeof(float); // 67 MB
  f16*   p16   = (f16*)p;                                                      // 134 MB
  const size_t need = (size_t)(p - ws) + (size_t)NROW * SQL * sizeof(f16);
  const bool spill = ws_size >= need;

  maskpack<<<8192, 256, 0, stream>>>(mask, mbits, NBATCH * SQL * SQL);
  proj<<<NROW / 16, 256, 0, stream>>>(inp, wk, wv, q16, kfrag, vfrag);
  if (spill) {
    fused<1><<<(NROW / 64) * KSPLIT, 256, 0, stream>>>(q16, kfrag, vfrag, mbits,
                                                       lpart, opart, p16, attn);
    finalize<1><<<NROW, 256, 0, stream>>>(p16, lpart, opart, attn, out);
  } else {
    fused<0><<<(NROW / 64) * KSPLIT, 256, 0, stream>>>(q16, kfrag, vfrag, mbits,
                                                       lpart, opart, p16, attn);
    finalize<0><<<NROW, 256, 0, stream>>>(p16, lpart, opart, attn, out);
  }
}